// Round 1
// baseline (537.845 us; speedup 1.0000x reference)
//
#include <hip/hip_runtime.h>

constexpr int N      = 100000;
constexpr int E      = 3200000;
constexpr int IN_CH  = 128;
constexpr int HID    = 16;
constexpr int OUT_CH = 64;

// ---------------- degree ----------------
__global__ void k_deg_count(const int* __restrict__ ei, float* __restrict__ deg) {
    int i = blockIdx.x * blockDim.x + threadIdx.x;
    int stride = gridDim.x * blockDim.x;
    const int* dst = ei + E;
    for (int e = i; e < E; e += stride)
        atomicAdd(&deg[dst[e]], 1.0f);
}

__global__ void k_deg_finish(float* __restrict__ deg) {
    int i = blockIdx.x * blockDim.x + threadIdx.x;
    if (i < N) deg[i] = rsqrtf(deg[i] + 1.0f);   // +1 self-loop; in-place -> dinv
}

// ---------------- layer1 linear: h1 = x @ W1 ; agg1 = dinv^2 * h1 (self-loop) ----------------
__global__ __launch_bounds__(256) void k_lin1(const float* __restrict__ x,
                                              const float* __restrict__ W1,
                                              const float* __restrict__ dinv,
                                              float* __restrict__ h1,
                                              float* __restrict__ agg1) {
    __shared__ float W1T[HID][IN_CH + 4];   // transposed, padded (bank spread)
    __shared__ float xs[16][IN_CH + 4];
    int t = threadIdx.x;
    // stage W1 (128x16 row-major) transposed
    for (int i = t; i < IN_CH * HID; i += 256) {
        int k = i >> 4, c = i & 15;
        W1T[c][k] = W1[i];
    }
    int rb = blockIdx.x * 16;
    const float* xblk = x + (size_t)rb * IN_CH;
    for (int i = t; i < 16 * IN_CH; i += 256)
        xs[i >> 7][i & 127] = xblk[i];     // fully coalesced: 2048 contiguous floats
    __syncthreads();

    int r = t >> 4, c = t & 15;
    int row = rb + r;
    if (row < N) {
        const float4* xr = (const float4*)xs[r];
        const float4* wr = (const float4*)W1T[c];
        float acc = 0.f;
        #pragma unroll
        for (int k4 = 0; k4 < IN_CH / 4; ++k4) {
            float4 a = xr[k4], w = wr[k4];
            acc += a.x * w.x + a.y * w.y + a.z * w.z + a.w * w.w;
        }
        int o = row * HID + c;
        h1[o] = acc;
        float di = dinv[row];
        agg1[o] = di * di * acc;
    }
}

// ---------------- edge scatter: agg[dst] += dinv[src]*dinv[dst] * h[src]  (16 ch) ----------------
__global__ void k_scatter(const int* __restrict__ ei, const float* __restrict__ dinv,
                          const float* __restrict__ h, float* __restrict__ agg) {
    int tid = blockIdx.x * blockDim.x + threadIdx.x;
    int lane = tid & (HID - 1);
    int g = tid >> 4;
    int gs = (gridDim.x * blockDim.x) >> 4;
    for (int e = g; e < E; e += gs) {
        int s = ei[e];
        int d = ei[E + e];
        float w = dinv[s] * dinv[d];
        atomicAdd(&agg[d * HID + lane], w * h[s * HID + lane]);
    }
}

// ---------------- bias+relu, self-loop init of agg2 ----------------
__global__ void k_relu_bias(float* __restrict__ agg1,        // in: agg1, out: h1r (in-place)
                            const float* __restrict__ b1,
                            const float* __restrict__ dinv,
                            float* __restrict__ agg2) {
    int i = blockIdx.x * blockDim.x + threadIdx.x;
    int stride = gridDim.x * blockDim.x;
    float4* a1 = (float4*)agg1;
    float4* a2 = (float4*)agg2;
    const float4* bv = (const float4*)b1;
    const int total = N * HID / 4;
    for (int q = i; q < total; q += stride) {
        float4 h = a1[q];
        float4 b = bv[q & 3];
        h.x = fmaxf(h.x + b.x, 0.f);
        h.y = fmaxf(h.y + b.y, 0.f);
        h.z = fmaxf(h.z + b.z, 0.f);
        h.w = fmaxf(h.w + b.w, 0.f);
        a1[q] = h;
        float di = dinv[q >> 2];
        float s = di * di;
        float4 o = {h.x * s, h.y * s, h.z * s, h.w * s};
        a2[q] = o;
    }
}

// ---------------- layer2 linear: out = agg2 @ W2 + b2 ----------------
__global__ __launch_bounds__(256) void k_lin2(const float* __restrict__ agg2,
                                              const float* __restrict__ W2,
                                              const float* __restrict__ b2,
                                              float* __restrict__ out) {
    __shared__ float W2s[HID * OUT_CH];   // 1024 floats
    __shared__ float as[16][HID];
    int t = threadIdx.x;
    for (int i = t; i < HID * OUT_CH; i += 256) W2s[i] = W2[i];
    int rb = blockIdx.x * 16;
    as[t >> 4][t & 15] = agg2[rb * HID + t];   // 256 contiguous floats
    __syncthreads();

    int r = t >> 4;
    int c4 = (t & 15) * 4;
    int row = rb + r;
    if (row < N) {
        float4 acc = *(const float4*)&b2[c4];
        #pragma unroll
        for (int k = 0; k < HID; ++k) {
            float a = as[r][k];
            float4 w = *(const float4*)&W2s[k * OUT_CH + c4];
            acc.x += a * w.x; acc.y += a * w.y; acc.z += a * w.z; acc.w += a * w.w;
        }
        *(float4*)&out[row * OUT_CH + c4] = acc;
    }
}

extern "C" void kernel_launch(void* const* d_in, const int* in_sizes, int n_in,
                              void* d_out, int out_size, void* d_ws, size_t ws_size,
                              hipStream_t stream) {
    const float* x  = (const float*)d_in[0];
    const int*   ei = (const int*)d_in[1];
    const float* W1 = (const float*)d_in[2];
    const float* b1 = (const float*)d_in[3];
    const float* W2 = (const float*)d_in[4];
    const float* b2 = (const float*)d_in[5];
    float* out = (float*)d_out;

    char* ws = (char*)d_ws;
    float* deg  = (float*)(ws);                 // N floats, becomes dinv in-place
    float* h1   = (float*)(ws + 400384);        // N*HID floats
    float* agg1 = (float*)(ws + 6800384);       // N*HID floats (becomes h1r in-place)
    float* agg2 = (float*)(ws + 13200384);      // N*HID floats

    hipMemsetAsync(deg, 0, N * sizeof(float), stream);
    k_deg_count <<<2048, 256, 0, stream>>>(ei, deg);
    k_deg_finish<<<(N + 255) / 256, 256, 0, stream>>>(deg);
    k_lin1      <<<(N + 15) / 16, 256, 0, stream>>>(x, W1, deg, h1, agg1);
    k_scatter   <<<4096, 256, 0, stream>>>(ei, deg, h1, agg1);
    k_relu_bias <<<(N * HID / 4 + 255) / 256, 256, 0, stream>>>(agg1, b1, deg, agg2);
    k_scatter   <<<4096, 256, 0, stream>>>(ei, deg, agg1, agg2);
    k_lin2      <<<(N + 15) / 16, 256, 0, stream>>>(agg2, W2, b2, out);
}